// Round 9
// baseline (3506.865 us; speedup 1.0000x reference)
//
#include <hip/hip_runtime.h>
#include <cstddef>

// Sparse 3D CNN. R8: conv32m -> 128-thread blocks, 2 waves x Mg=4 groups.
// R7 analysis: B-frag L2 traffic (512KB/wave, 5GB/c2-dispatch ~143us) was the
// largest wall and 32 MFMA-cyc/tap couldn't hide B-load latency. Mg=4 halves
// B traffic, gives 64 MFMA-cyc between B-pairs, and pairs of waves hit L1 on
// the shared tap frags. LDS halo (40B/voxel, conflict-free) unchanged ->
// 37.2KB, 4 blocks/CU.
// R5-R7: MFMA bf16 hi/lo split (2-mfma K-pack => exact-enough 4-term product).
// Chain: 50,60,65 -> c1 47,57,62 -> c2 44,54,59 -> p1 40,50,55 -> c3 37,47,52
// -> c4 34,44,49 -> p2 30,40,45 -> c5 27,37,42 -> c6 24,34,39 -> c7 21,31,36
// -> p3 17,27,32 ; flatten 14688 -> FC 1000 -> 1000 -> 1

#define NEGSLOPE 0.01f
#define NINF (-3.0e38f)

// shared tile geometry: 4x4x16 out, 7x7x19 halo
#define TZ 4
#define TY 4
#define TXT 16
#define IZ 7
#define IY 7
#define IX 19
#define NV (IZ*IY*IX)    // 931 voxels; conv32m: 931*40B = 37.2 KB

typedef __attribute__((ext_vector_type(8)))  short    short8;    // 8 bf16
typedef __attribute__((ext_vector_type(4)))  unsigned uint4v;
typedef __attribute__((ext_vector_type(16))) float    floatx16;  // 32x32 acc

__device__ __forceinline__ float lrelu(float v) { return v >= 0.f ? v : NEGSLOPE * v; }

__device__ __forceinline__ unsigned short f2bf(float f) {
  unsigned b = __float_as_uint(f);
  return (unsigned short)((b + 0x7fffu + ((b >> 16) & 1u)) >> 16);   // RNE
}
__device__ __forceinline__ float bf2f(unsigned short h) {
  return __uint_as_float(((unsigned)h) << 16);
}
__device__ __forceinline__ unsigned splitpair(float a, float b, unsigned& lo) {
  unsigned short ha = f2bf(a), hb = f2bf(b);
  unsigned short la = f2bf(a - bf2f(ha)), lb = f2bf(b - bf2f(hb));
  lo = (unsigned)la | ((unsigned)lb << 16);
  return (unsigned)ha | ((unsigned)hb << 16);
}

// load A-frag (8 bf16) from LDS at 40B voxel stride; oct 0 = hi, oct 1 = lo
__device__ __forceinline__ short8 ld_frag(const uint2* s2, int v, int oct) {
  uint2 u0 = s2[v * 5 + oct * 2];
  uint2 u1 = s2[v * 5 + oct * 2 + 1];
  uint4v t; t.x = u0.x; t.y = u0.y; t.z = u1.x; t.w = u1.y;
  return __builtin_bit_cast(short8, t);
}

// ---------------- scatter (last-write-wins), full batch ----------------
__global__ void k_claim(const int* __restrict__ coors, unsigned* __restrict__ claim, int N) {
  int i = blockIdx.x * blockDim.x + threadIdx.x;
  if (i >= N) return;
  int b = coors[4*i], z = coors[4*i+1], y = coors[4*i+2], x = coors[4*i+3];
  int v = ((b*50 + z)*60 + y)*65 + x;
  atomicMax(&claim[v], (unsigned)(i + 1));
}

__global__ void k_scatter(const int* __restrict__ coors, const float* __restrict__ feat,
                          const unsigned* __restrict__ claim,
                          float* __restrict__ x0, float* __restrict__ m0, int N) {
  int i = blockIdx.x * blockDim.x + threadIdx.x;
  if (i >= N) return;
  int b = coors[4*i], z = coors[4*i+1], y = coors[4*i+2], x = coors[4*i+3];
  int v = ((b*50 + z)*60 + y)*65 + x;
  m0[v] = 1.f;
  if (claim[v] == (unsigned)(i + 1)) x0[v] = feat[i];
}

// ---------------- weight repack (c1/c7): w[co][ci][k64] -> wr[k64][ci][co] --------
__global__ void k_repack(const float* __restrict__ w, float* __restrict__ wr, int CI, int CO) {
  int i = blockIdx.x * blockDim.x + threadIdx.x;
  int tot = CO * CI * 64;
  if (i >= tot) return;
  int k = i & 63;
  int ci = (i >> 6) % CI;
  int co = i / (64 * CI);
  wr[(k * CI + ci) * CO + co] = w[i];
}

// ---------------- MFMA B-fragment table build for 32->32 layers ----------------
// tbl layout: [(tap*4 + pass)*2 + pack][lane 0..63][8 bf16]  (1 KB per frag)
// pack0: k 0..7 = wh(ci), k 8..15 = wl(ci); pack1 swapped. ci = pass*8 + (k&7).
__global__ void k_repack_mfma(const float* __restrict__ w, unsigned short* __restrict__ tbl) {
  int i = blockIdx.x * blockDim.x + threadIdx.x;   // 0..32767
  if (i >= 64*4*2*64) return;
  int lane = i & 63; int t = i >> 6;
  int pack = t & 1; t >>= 1;
  int pass = t & 3; int tap = t >> 2;
  int co = lane & 31; int oct = lane >> 5;
#pragma unroll
  for (int j = 0; j < 8; ++j) {
    int k = oct * 8 + j;
    int ci = pass * 8 + (k & 7);
    int part = ((k >> 3) ^ pack) & 1;
    float wv = w[((co * 32 + ci) << 6) + tap];
    unsigned short wh = f2bf(wv);
    unsigned short r = part ? f2bf(wv - bf2f(wh)) : wh;
    tbl[(size_t)i * 8 + j] = r;
  }
}

// ---------------- separable mask dilation ----------------
__global__ void kd_z(const float* __restrict__ in, float* __restrict__ o,
                     int Zi, int Yi, int Xi, int Zo, int K, int nI) {
  int gid = blockIdx.x * blockDim.x + threadIdx.x;
  int perOut = Zo * Yi * Xi;
  if (gid >= nI * perOut) return;
  int item = gid / perOut;
  int r = gid - item * perOut;
  int x = r % Xi; int t = r / Xi;
  int y = t % Yi; int z = t / Yi;
  const float* ib = in + (size_t)item * Zi * Yi * Xi;
  float mx = 0.f;
  for (int d = 0; d < K; d++) mx = fmaxf(mx, ib[((z + d) * Yi + y) * Xi + x]);
  o[gid] = mx;
}

__global__ void kd_y(const float* __restrict__ in, float* __restrict__ o,
                     int Zo, int Yi, int Xi, int Yo, int K, int nI) {
  int gid = blockIdx.x * blockDim.x + threadIdx.x;
  int perOut = Zo * Yo * Xi;
  if (gid >= nI * perOut) return;
  int item = gid / perOut;
  int r = gid - item * perOut;
  int x = r % Xi; int t = r / Xi;
  int y = t % Yo; int z = t / Yo;
  const float* ib = in + (size_t)item * Zo * Yi * Xi;
  float mx = 0.f;
  for (int d = 0; d < K; d++) mx = fmaxf(mx, ib[(z * Yi + y + d) * Xi + x]);
  o[gid] = mx;
}

__global__ void kd_x(const float* __restrict__ in, float* __restrict__ o,
                     int Zo, int Yo, int Xi, int Xo, int K, int nI) {
  int gid = blockIdx.x * blockDim.x + threadIdx.x;
  int perOut = Zo * Yo * Xo;
  if (gid >= nI * perOut) return;
  int item = gid / perOut;
  int r = gid - item * perOut;
  int x = r % Xo; int t = r / Xo;
  int y = t % Yo; int z = t / Yo;
  const float* ib = in + (size_t)item * Zo * Yo * Xi;
  float mx = 0.f;
  for (int d = 0; d < K; d++) mx = fmaxf(mx, ib[(z * Yo + y) * Xi + x + d]);
  o[gid] = mx;
}

// ---------------- MFMA conv 32->32 ----------------
// Block = 4x4x16 output tile (256 voxels = 8 M-groups), 128 threads = 2 waves,
// each wave owns 4 groups. Halo 7x7x19 in LDS at 40 B/voxel, 4 passes of 8 ci.
// Per tap per wave: 4 A-frags (2x ds_read_b64 each), 2 B-frags (global L2/L1),
// 8 mfma 32x32x16 (pack0/1 hi/lo).
__global__ __launch_bounds__(128, 2)
void k_conv32m(const float* __restrict__ in, const unsigned short* __restrict__ tbl,
               const float* __restrict__ bias, const float* __restrict__ mo,
               float* __restrict__ out,
               int Zi, int Yi, int Xi, int Zo, int Yo, int Xo,
               int tilesZ, int tilesY, int tilesX) {
  __shared__ unsigned sU[NV * 10];   // 37.2 KB
  const int perIn = Zi * Yi * Xi;
  const int perOut = Zo * Yo * Xo;
  int bid = blockIdx.x;
  int txi = bid % tilesX; bid /= tilesX;
  int tyi = bid % tilesY; bid /= tilesY;
  int tzi = bid % tilesZ; int item = bid / tilesZ;
  const int z0 = tzi * TZ, y0 = tyi * TY, x0 = txi * TXT;
  const int tid = threadIdx.x;
  const int lane = tid & 63;
  const int col = lane & 31;     // co (B n-index) and A-row m
  const int oct = lane >> 5;
  const int wv  = tid >> 6;      // wave 0..1

  int lvB0, lvB1, lvB2, lvB3;
  {
    int vt0 = (4*wv + 0)*32 + col;
    int vt1 = (4*wv + 1)*32 + col;
    int vt2 = (4*wv + 2)*32 + col;
    int vt3 = (4*wv + 3)*32 + col;
    lvB0 = ((vt0 >> 6)*IY + ((vt0 >> 4) & 3))*IX + (vt0 & 15);
    lvB1 = ((vt1 >> 6)*IY + ((vt1 >> 4) & 3))*IX + (vt1 & 15);
    lvB2 = ((vt2 >> 6)*IY + ((vt2 >> 4) & 3))*IX + (vt2 & 15);
    lvB3 = ((vt3 >> 6)*IY + ((vt3 >> 4) & 3))*IX + (vt3 & 15);
  }

  floatx16 acc0, acc1, acc2, acc3;
#pragma unroll
  for (int r = 0; r < 16; ++r) { acc0[r] = 0.f; acc1[r] = 0.f; acc2[r] = 0.f; acc3[r] = 0.f; }

  const float* inb = in + (size_t)item * perIn * 32;
  const char* tb = (const char*)tbl + lane * 16;
  uint2* s2 = (uint2*)sU;

#pragma unroll 1
  for (int p = 0; p < 4; ++p) {
    __syncthreads();
    for (int idx = tid; idx < NV; idx += 128) {
      int iz = idx / (IY * IX); int r = idx - iz * (IY * IX);
      int iy = r / IX; int ix = r - iy * IX;
      int gz = z0 + iz, gy = y0 + iy, gx = x0 + ix;
      float4 f0 = make_float4(0.f,0.f,0.f,0.f), f1 = make_float4(0.f,0.f,0.f,0.f);
      if (gz < Zi && gy < Yi && gx < Xi) {
        const float* vp = inb + (size_t)((gz * Yi + gy) * Xi + gx) * 32 + p * 8;
        f0 = *(const float4*)vp;
        f1 = *(const float4*)(vp + 4);
      }
      unsigned l0, l1, l2, l3;
      unsigned h0 = splitpair(f0.x, f0.y, l0);
      unsigned h1 = splitpair(f0.z, f0.w, l1);
      unsigned h2 = splitpair(f1.x, f1.y, l2);
      unsigned h3 = splitpair(f1.z, f1.w, l3);
      s2[idx * 5 + 0] = make_uint2(h0, h1);
      s2[idx * 5 + 1] = make_uint2(h2, h3);
      s2[idx * 5 + 2] = make_uint2(l0, l1);
      s2[idx * 5 + 3] = make_uint2(l2, l3);
    }
    __syncthreads();

    const char* tp = tb + (size_t)p * 2048;
#pragma unroll 2
    for (int tap = 0; tap < 64; ++tap) {
      int kz = tap >> 4, ky = (tap >> 2) & 3, kx = tap & 3;
      int sOff = (kz * IY + ky) * IX + kx;
      short8 b0 = *(const short8*)(tp + (size_t)tap * 8192);
      short8 b1 = *(const short8*)(tp + (size_t)tap * 8192 + 1024);
      short8 a0 = ld_frag(s2, lvB0 + sOff, oct);
      short8 a1 = ld_frag(s2, lvB1 + sOff, oct);
      short8 a2 = ld_frag(s2, lvB2 + sOff, oct);
      short8 a3 = ld_frag(s2, lvB3 + sOff, oct);
      acc0 = __builtin_amdgcn_mfma_f32_32x32x16_bf16(a0, b0, acc0, 0, 0, 0);
      acc0 = __builtin_amdgcn_mfma_f32_32x32x16_bf16(a0, b1, acc0, 0, 0, 0);
      acc1 = __builtin_amdgcn_mfma_f32_32x32x16_bf16(a1, b0, acc1, 0, 0, 0);
      acc1 = __builtin_amdgcn_mfma_f32_32x32x16_bf16(a1, b1, acc1, 0, 0, 0);
      acc2 = __builtin_amdgcn_mfma_f32_32x32x16_bf16(a2, b0, acc2, 0, 0, 0);
      acc2 = __builtin_amdgcn_mfma_f32_32x32x16_bf16(a2, b1, acc2, 0, 0, 0);
      acc3 = __builtin_amdgcn_mfma_f32_32x32x16_bf16(a3, b0, acc3, 0, 0, 0);
      acc3 = __builtin_amdgcn_mfma_f32_32x32x16_bf16(a3, b1, acc3, 0, 0, 0);
    }
  }

  // epilogue: C/D layout col=lane&31 (co), row m=(reg&3)+8*(reg>>2)+4*oct
  const float bco = bias[col];
#pragma unroll
  for (int gg = 0; gg < 4; ++gg) {
    int vtb = (4*wv + gg) * 32;
#pragma unroll
    for (int rg = 0; rg < 16; ++rg) {
      int row = (rg & 3) + 8 * (rg >> 2) + 4 * oct;
      int vt = vtb + row;
      int oz = vt >> 6, oy = (vt >> 4) & 3, ox = vt & 15;
      int gz = z0 + oz, gy = y0 + oy, gx = x0 + ox;
      if (gz < Zo && gy < Yo && gx < Xo) {
        int ov = item * perOut + (gz * Yo + gy) * Xo + gx;
        float val = (gg == 0) ? acc0[rg] : (gg == 1) ? acc1[rg] : (gg == 2) ? acc2[rg] : acc3[rg];
        bool act = mo[ov] > 0.f;
        out[(size_t)ov * 32 + col] = lrelu(act ? (val + bco) : 0.f);
      }
    }
  }
}

// ---------------- LDS-tiled conv 1->32 (c1), weights in LDS ----------------
__global__ __launch_bounds__(256, 2)
void k_conv1t(const float* __restrict__ in, const float* __restrict__ wr,
              const float* __restrict__ bias, const float* __restrict__ mo,
              float* __restrict__ out,
              int Zi, int Yi, int Xi, int Zo, int Yo, int Xo,
              int tilesZ, int tilesY, int tilesX) {
  __shared__ float sinf[NV];
  __shared__ float4 wsh[512];   // 64 taps x 8 co-quads
  {
    const float4* wr4 = (const float4*)wr;
    for (int idx = threadIdx.x; idx < 512; idx += 256) wsh[idx] = wr4[idx];
  }
  const int perIn = Zi * Yi * Xi;
  const int perOut = Zo * Yo * Xo;
  int bid = blockIdx.x;
  int txi = bid % tilesX; bid /= tilesX;
  int tyi = bid % tilesY; bid /= tilesY;
  int tzi = bid % tilesZ; int item = bid / tilesZ;
  const int z0 = tzi * TZ, y0 = tyi * TY, x0 = txi * TXT;
  const int tid = threadIdx.x;
  const int ox = tid & 15, oy = (tid >> 4) & 3, oz = tid >> 6;

  const float* inb = in + (size_t)item * perIn;
  for (int idx = tid; idx < NV; idx += 256) {
    int iz = idx / (IY * IX); int r = idx - iz * (IY * IX);
    int iy = r / IX; int ix = r - iy * IX;
    int gz = z0 + iz, gy = y0 + iy, gx = x0 + ix;
    float val = 0.f;
    if (gz < Zi && gy < Yi && gx < Xi)
      val = inb[(size_t)((gz * Yi + gy) * Xi + gx)];
    sinf[idx] = val;
  }
  __syncthreads();

  float4 acc[8];
#pragma unroll
  for (int j = 0; j < 8; ++j) acc[j] = make_float4(0.f, 0.f, 0.f, 0.f);

#pragma unroll 1
  for (int tap = 0; tap < 64; ++tap) {
    int kz = tap >> 4, ky = (tap >> 2) & 3, kx = tap & 3;
    int lv = ((oz + kz) * IY + (oy + ky)) * IX + (ox + kx);
    float av = sinf[lv];
#pragma unroll
    for (int j = 0; j < 8; ++j) {
      float4 wvv = wsh[tap * 8 + j];
      acc[j].x = fmaf(av, wvv.x, acc[j].x);
      acc[j].y = fmaf(av, wvv.y, acc[j].y);
      acc[j].z = fmaf(av, wvv.z, acc[j].z);
      acc[j].w = fmaf(av, wvv.w, acc[j].w);
    }
  }

  int gz = z0 + oz, gy = y0 + oy, gx = x0 + ox;
  if (gz < Zo && gy < Yo && gx < Xo) {
    int ov = item * perOut + (gz * Yo + gy) * Xo + gx;
    bool act = mo[ov] > 0.f;
    const float4* b4 = (const float4*)bias;
    float* op = out + (size_t)ov * 32;
#pragma unroll
    for (int j = 0; j < 8; ++j) {
      float4 r = acc[j]; float4 bj = b4[j];
      r.x = lrelu(act ? (r.x + bj.x) : 0.f);
      r.y = lrelu(act ? (r.y + bj.y) : 0.f);
      r.z = lrelu(act ? (r.z + bj.z) : 0.f);
      r.w = lrelu(act ? (r.w + bj.w) : 0.f);
      *(float4*)(op + j * 4) = r;
    }
  }
}

// ---------------- LDS-tiled conv 32->1 (c7), weights in LDS ----------------
__global__ __launch_bounds__(256, 2)
void k_conv7t(const float* __restrict__ in, const float* __restrict__ wr,
              const float* __restrict__ bias, const float* __restrict__ mo,
              float* __restrict__ out,
              int Zi, int Yi, int Xi, int Zo, int Yo, int Xo,
              int tilesZ, int tilesY, int tilesX) {
  __shared__ float4 sin4[4][NV];
  __shared__ float4 wsh[512];   // 64 taps x 8 ci-quads
  {
    const float4* wr4 = (const float4*)wr;
    for (int idx = threadIdx.x; idx < 512; idx += 256) wsh[idx] = wr4[idx];
  }
  const int perIn = Zi * Yi * Xi;
  const int perOut = Zo * Yo * Xo;
  int bid = blockIdx.x;
  int txi = bid % tilesX; bid /= tilesX;
  int tyi = bid % tilesY; bid /= tilesY;
  int tzi = bid % tilesZ; int item = bid / tilesZ;
  const int z0 = tzi * TZ, y0 = tyi * TY, x0 = txi * TXT;
  const int tid = threadIdx.x;
  const int ox = tid & 15, oy = (tid >> 4) & 3, oz = tid >> 6;

  const float* inb = in + (size_t)item * perIn * 32;
  float acc = 0.f;

#pragma unroll 1
  for (int h = 0; h < 2; ++h) {
    __syncthreads();
    for (int idx = tid; idx < NV * 4; idx += 256) {
      int q = idx / NV; int v = idx - q * NV;
      int iz = v / (IY * IX); int r = v - iz * (IY * IX);
      int iy = r / IX; int ix = r - iy * IX;
      int gz = z0 + iz, gy = y0 + iy, gx = x0 + ix;
      float4 val = make_float4(0.f, 0.f, 0.f, 0.f);
      if (gz < Zi && gy < Yi && gx < Xi)
        val = *(const float4*)(inb + (size_t)((gz * Yi + gy) * Xi + gx) * 32 + h * 16 + q * 4);
      sin4[q][v] = val;
    }
    __syncthreads();
#pragma unroll 1
    for (int tap = 0; tap < 64; ++tap) {
      int kz = tap >> 4, ky = (tap >> 2) & 3, kx = tap & 3;
      int lv = ((oz + kz) * IY + (oy + ky)) * IX + (ox + kx);
      float4 a0 = sin4[0][lv];
      float4 a1 = sin4[1][lv];
      float4 a2 = sin4[2][lv];
      float4 a3 = sin4[3][lv];
      float4 w0 = wsh[tap * 8 + h * 4 + 0];
      float4 w1 = wsh[tap * 8 + h * 4 + 1];
      float4 w2 = wsh[tap * 8 + h * 4 + 2];
      float4 w3 = wsh[tap * 8 + h * 4 + 3];
      acc += a0.x*w0.x + a0.y*w0.y + a0.z*w0.z + a0.w*w0.w
           + a1.x*w1.x + a1.y*w1.y + a1.z*w1.z + a1.w*w1.w
           + a2.x*w2.x + a2.y*w2.y + a2.z*w2.z + a2.w*w2.w
           + a3.x*w3.x + a3.y*w3.y + a3.z*w3.z + a3.w*w3.w;
    }
  }

  int gz = z0 + oz, gy = y0 + oy, gx = x0 + ox;
  if (gz < Zo && gy < Yo && gx < Xo) {
    int ov = item * perOut + (gz * Yo + gy) * Xo + gx;
    bool act = mo[ov] > 0.f;
    out[ov] = lrelu(act ? (acc + bias[0]) : 0.f);
  }
}

// ---------------- batched separable sparse maxpool (C=32, float4/thread) -----------
__global__ void k_pool_z(const float* __restrict__ in, const float* __restrict__ m,
                         float* __restrict__ out, int Zi, int Yi, int Xi, int Zo, int nI) {
  int gid = blockIdx.x * blockDim.x + threadIdx.x;
  int perOut = Zo * Yi * Xi;
  int tot = nI * perOut * 8;
  if (gid >= tot) return;
  int c4 = gid & 7; int v = gid >> 3;
  int item = v / perOut;
  int r = v - item * perOut;
  int x = r % Xi; int t = r / Xi;
  int y = t % Yi; int z = t / Yi;
  int ib = item * Zi * Yi * Xi;
  float4 acc = {NINF, NINF, NINF, NINF};
  for (int j = 0; j < 5; j++) {
    int vi = ib + ((z + j)*Yi + y)*Xi + x;
    if (m[vi] > 0.f) {
      float4 val = *(const float4*)(in + (size_t)vi*32 + c4*4);
      acc.x = fmaxf(acc.x, val.x); acc.y = fmaxf(acc.y, val.y);
      acc.z = fmaxf(acc.z, val.z); acc.w = fmaxf(acc.w, val.w);
    }
  }
  *(float4*)(out + (size_t)v*32 + c4*4) = acc;
}

__global__ void k_pool_y(const float* __restrict__ in, float* __restrict__ out,
                         int Z, int Yi, int Xi, int Yo, int nI) {
  int gid = blockIdx.x * blockDim.x + threadIdx.x;
  int perOut = Z * Yo * Xi;
  int tot = nI * perOut * 8;
  if (gid >= tot) return;
  int c4 = gid & 7; int v = gid >> 3;
  int item = v / perOut;
  int r = v - item * perOut;
  int x = r % Xi; int t = r / Xi;
  int y = t % Yo; int z = t / Yo;
  int ib = item * Z * Yi * Xi;
  float4 acc = {NINF, NINF, NINF, NINF};
  for (int j = 0; j < 5; j++) {
    int vi = ib + (z*Yi + y + j)*Xi + x;
    float4 val = *(const float4*)(in + (size_t)vi*32 + c4*4);
    acc.x = fmaxf(acc.x, val.x); acc.y = fmaxf(acc.y, val.y);
    acc.z = fmaxf(acc.z, val.z); acc.w = fmaxf(acc.w, val.w);
  }
  *(float4*)(out + (size_t)v*32 + c4*4) = acc;
}

__global__ void k_pool_x(const float* __restrict__ in, const float* __restrict__ mp,
                         float* __restrict__ out, int Z, int Y, int Xi, int Xo, int nI) {
  int gid = blockIdx.x * blockDim.x + threadIdx.x;
  int perOut = Z * Y * Xo;
  int tot = nI * perOut * 8;
  if (gid >= tot) return;
  int c4 = gid & 7; int v = gid >> 3;
  int item = v / perOut;
  int r = v - item * perOut;
  int x = r % Xo; int t = r / Xo;
  int y = t % Y; int z = t / Y;
  int ib = item * Z * Y * Xi;
  float4 acc = {NINF, NINF, NINF, NINF};
  for (int j = 0; j < 5; j++) {
    int vi = ib + (z*Y + y)*Xi + x + j;
    float4 val = *(const float4*)(in + (size_t)vi*32 + c4*4);
    acc.x = fmaxf(acc.x, val.x); acc.y = fmaxf(acc.y, val.y);
    acc.z = fmaxf(acc.z, val.z); acc.w = fmaxf(acc.w, val.w);
  }
  bool act = mp[v] > 0.f;
  float4 rr;
  rr.x = act ? acc.x : 0.f; rr.y = act ? acc.y : 0.f;
  rr.z = act ? acc.z : 0.f; rr.w = act ? acc.w : 0.f;
  *(float4*)(out + (size_t)v*32 + c4*4) = rr;
}

// ---------------- final pool (C=1, direct 5^3), 21,31,36 -> 17,27,32, batched ------
__global__ void k_pool3(const float* __restrict__ xin, const float* __restrict__ m,
                        const float* __restrict__ mp, float* __restrict__ out, int nI) {
  int gid = blockIdx.x * blockDim.x + threadIdx.x;
  int perOut = 17 * 27 * 32;
  int tot = nI * perOut;
  if (gid >= tot) return;
  int item = gid / perOut;
  int r = gid - item * perOut;
  int x = r & 31; int t = r >> 5;
  int y = t % 27; int z = t / 27;
  const float* xb = xin + (size_t)item * 23436;
  const float* mb = m + (size_t)item * 23436;
  float acc = NINF;
  for (int dz = 0; dz < 5; dz++)
    for (int dy = 0; dy < 5; dy++) {
      const float* rowx = xb + (size_t)(((z + dz)*31 + y + dy)*36 + x);
      const float* rowm = mb + (size_t)(((z + dz)*31 + y + dy)*36 + x);
      for (int dx = 0; dx < 5; dx++)
        if (rowm[dx] > 0.f) acc = fmaxf(acc, rowx[dx]);
    }
  out[gid] = (mp[gid] > 0.f) ? acc : 0.f;
}

// ---------------- FC split-K partial + finalize ----------------
__global__ __launch_bounds__(256, 4)
void k_fc_part(const float* __restrict__ X, const float* __restrict__ Wm,
               float* __restrict__ part, int K, int Ncol, int Kc) {
  __shared__ float sm[16][16][8];
  int ks = blockIdx.y;
  int k0 = ks * Kc;
  int k1 = k0 + Kc; if (k1 > K) k1 = K;
  int cl = threadIdx.x & 15;
  int kt = threadIdx.x >> 4;
  int col = blockIdx.x * 16 + cl;
  float a0=0.f,a1=0.f,a2=0.f,a3=0.f,a4=0.f,a5=0.f,a6=0.f,a7=0.f;
  if (col < Ncol) {
    for (int k = k0 + kt; k < k1; k += 16) {
      float w = Wm[(size_t)k * Ncol + col];
      a0 += X[0 * K + k] * w; a1 += X[1 * K + k] * w;
      a2 += X[2 * K + k] * w; a3 += X[3 * K + k] * w;
      a4 += X[4 * K + k] * w; a5 += X[5 * K + k] * w;
      a6 += X[6 * K + k] * w; a7 += X[7 * K + k] * w;
    }
  }
  sm[kt][cl][0]=a0; sm[kt][cl][1]=a1; sm[kt][cl][2]=a2; sm[kt][cl][3]=a3;
  sm[kt][cl][4]=a4; sm[kt][cl][5]=a5; sm[kt][cl][6]=a6; sm[kt][cl][7]=a7;
  __syncthreads();
  if (threadIdx.x < 128) {
    int c = threadIdx.x & 15;
    int b = threadIdx.x >> 4;
    float s = 0.f;
#pragma unroll
    for (int k = 0; k < 16; k++) s += sm[k][c][b];
    int cc = blockIdx.x * 16 + c;
    if (cc < Ncol) part[((size_t)ks * 8 + b) * Ncol + cc] = s;
  }
}

__global__ void k_fc_fin(const float* __restrict__ part, int ns,
                         const float* __restrict__ bias, float* __restrict__ out, int Ncol) {
  int i = blockIdx.x * blockDim.x + threadIdx.x;
  if (i >= 8 * Ncol) return;
  int b = i / Ncol;
  int c = i - b * Ncol;
  float s = 0.f;
  for (int ks = 0; ks < ns; ks++) s += part[((size_t)ks * 8 + b) * Ncol + c];
  out[i] = lrelu(s + bias[c]);
}

// last FC (K=1000 -> 1), small
__global__ __launch_bounds__(256, 4)
void k_fc(const float* __restrict__ X, const float* __restrict__ Wm,
          const float* __restrict__ bias, float* __restrict__ out,
          int K, int Ncol) {
  __shared__ float sm[16][16][8];
  int cl = threadIdx.x & 15;
  int kt = threadIdx.x >> 4;
  int col = blockIdx.x * 16 + cl;
  float a0=0.f,a1=0.f,a2=0.f,a3=0.f,a4=0.f,a5=0.f,a6=0.f,a7=0.f;
  if (col < Ncol) {
    for (int k = kt; k < K; k += 16) {
      float w = Wm[(size_t)k * Ncol + col];
      a0 += X[0 * K + k] * w; a1 += X[1 * K + k] * w;
      a2 += X[2 * K + k] * w; a3 += X[3 * K + k] * w;
      a4 += X[4 * K + k] * w; a5 += X[5 * K + k] * w;
      a6 += X[6 * K + k] * w; a7 += X[7 * K + k] * w;
    }
  }
  sm[kt][cl][0]=a0; sm[kt][cl][1]=a1; sm[kt][cl][2]=a2; sm[kt][cl][3]=a3;
  sm[kt][cl][4]=a4; sm[kt][cl][5]=a5; sm[kt][cl][6]=a6; sm[kt][cl][7]=a7;
  __syncthreads();
  if (threadIdx.x < 128) {
    int c = threadIdx.x & 15;
    int b = threadIdx.x >> 4;
    float s = 0.f;
#pragma unroll
    for (int k = 0; k < 16; k++) s += sm[k][c][b];
    int cc = blockIdx.x * 16 + c;
    if (cc < Ncol) out[b * Ncol + cc] = lrelu(s + bias[cc]);
  }
}

// ---------------- host ----------------
static inline int G256(long long n) { return (int)((n + 255) / 256); }

extern "C" void kernel_launch(void* const* d_in, const int* in_sizes, int n_in,
                              void* d_out, int out_size, void* d_ws, size_t ws_size,
                              hipStream_t stream) {
  const float* feat  = (const float*)d_in[0];
  const int*   coors = (const int*)d_in[1];
  const float* w1 = (const float*)d_in[3];  const float* b1 = (const float*)d_in[4];
  const float* w2 = (const float*)d_in[5];  const float* b2 = (const float*)d_in[6];
  const float* w3 = (const float*)d_in[7];  const float* b3 = (const float*)d_in[8];
  const float* w4 = (const float*)d_in[9];  const float* b4 = (const float*)d_in[10];
  const float* w5 = (const float*)d_in[11]; const float* b5 = (const float*)d_in[12];
  const float* w6 = (const float*)d_in[13]; const float* b6 = (const float*)d_in[14];
  const float* w7 = (const float*)d_in[15]; const float* b7 = (const float*)d_in[16];
  const float* W8 = (const float*)d_in[17]; const float* b8 = (const float*)d_in[18];
  const float* W9 = (const float*)d_in[19]; const float* b9 = (const float*)d_in[20];
  const float* W10= (const float*)d_in[21]; const float* b10= (const float*)d_in[22];
  float* out = (float*)d_out;

  char* ws = (char*)d_ws;
  size_t off = 0;
  auto alloc = [&](size_t nfloats) -> float* {
    float* p = (float*)(ws + off);
    off += ((nfloats * 4 + 1023) / 1024) * 1024;
    return p;
  };

  // ---- fixed allocations ----
  float* x0  = alloc(1560000);
  float* m0  = alloc(1560000);
  float* m1  = alloc(8 * 166098);
  float* m2  = alloc(8 * 140184);
  float* mp1 = alloc(8 * 110000);
  float* m3  = alloc(8 * 90428);
  float* m4  = alloc(8 * 73304);
  float* mp2 = alloc(8 * 54000);
  float* m5  = alloc(8 * 41958);
  float* m6  = alloc(8 * 31824);
  float* m7  = alloc(8 * 23436);
  float* mp3 = alloc(8 * 14688);
  float* p3  = alloc(8 * 14688);
  float* dt1 = alloc(8 * 183300);   // separable-dilate temps
  float* dt2 = alloc(8 * 174135);
  float* wr1 = alloc(2048);
  float* wr7 = alloc(2048);
  unsigned short* tb2 = (unsigned short*)alloc(131072);   // 512 KB B-frag tables
  unsigned short* tb3 = (unsigned short*)alloc(131072);
  unsigned short* tb4 = (unsigned short*)alloc(131072);
  unsigned short* tb5 = (unsigned short*)alloc(131072);
  unsigned short* tb6 = (unsigned short*)alloc(131072);
  float* part= alloc(64000);
  float* h8  = alloc(8000);
  float* h9  = alloc(8000);
  size_t fixedOff = off;

  // ---- pick group size G from remaining workspace ----
  const size_t perItemAB = ((size_t)5315136*4 + 1023)/1024*1024
                         + ((size_t)4485888*4 + 1023)/1024*1024
                         + ((size_t)23436*4 + 1023)/1024*1024;
  int G = 0;
  for (int g : {8, 4, 2, 1})
    if (fixedOff + (size_t)g * perItemAB <= ws_size) { G = g; break; }
  if (G == 0) return;

  float* A  = alloc((size_t)G * 5315136);
  float* Bb = alloc((size_t)G * 4485888);
  float* x7 = alloc((size_t)G * 23436);
  unsigned* claim = (unsigned*)A;   // claim aliases A (dead before first conv use)

  // ---- init ----
  hipMemsetAsync(claim, 0, 1560000 * 4, stream);
  hipMemsetAsync(x0,    0, 1560000 * 4, stream);
  hipMemsetAsync(m0,    0, 1560000 * 4, stream);

  k_repack<<<G256(32*1*64),  256, 0, stream>>>(w1, wr1, 1, 32);
  k_repack<<<G256(1*32*64),  256, 0, stream>>>(w7, wr7, 32, 1);
  k_repack_mfma<<<128, 256, 0, stream>>>(w2, tb2);
  k_repack_mfma<<<128, 256, 0, stream>>>(w3, tb3);
  k_repack_mfma<<<128, 256, 0, stream>>>(w4, tb4);
  k_repack_mfma<<<128, 256, 0, stream>>>(w5, tb5);
  k_repack_mfma<<<128, 256, 0, stream>>>(w6, tb6);

  const int N = 80000;
  k_claim  <<<G256(N), 256, 0, stream>>>(coors, claim, N);
  k_scatter<<<G256(N), 256, 0, stream>>>(coors, feat, claim, x0, m0, N);

  // ---- separable mask dilations, batched over 8 items ----
  auto dil3 = [&](const float* src, float* dst,
                  int Zi, int Yi, int Xi, int Zo, int Yo, int Xo, int K) {
    kd_z<<<G256((long long)8*Zo*Yi*Xi), 256, 0, stream>>>(src, dt1, Zi,Yi,Xi, Zo, K, 8);
    kd_y<<<G256((long long)8*Zo*Yo*Xi), 256, 0, stream>>>(dt1, dt2, Zo,Yi,Xi, Yo, K, 8);
    kd_x<<<G256((long long)8*Zo*Yo*Xo), 256, 0, stream>>>(dt2, dst, Zo,Yo,Xi, Xo, K, 8);
  };
  dil3(m0,  m1,  50,60,65, 47,57,62, 4);
  dil3(m1,  m2,  47,57,62, 44,54,59, 4);
  dil3(m2,  mp1, 44,54,59, 40,50,55, 5);
  dil3(mp1, m3,  40,50,55, 37,47,52, 4);
  dil3(m3,  m4,  37,47,52, 34,44,49, 4);
  dil3(m4,  mp2, 34,44,49, 30,40,45, 5);
  dil3(mp2, m5,  30,40,45, 27,37,42, 4);
  dil3(m5,  m6,  27,37,42, 24,34,39, 4);
  dil3(m6,  m7,  24,34,39, 21,31,36, 4);
  dil3(m7,  mp3, 21,31,36, 17,27,32, 5);

  auto conv32 = [&](const float* in, const unsigned short* tbl, const float* bias,
                    const float* mo, float* o,
                    int Zi, int Yi, int Xi, int Zo, int Yo, int Xo, int nI) {
    int tz = (Zo + TZ - 1) / TZ, ty = (Yo + TY - 1) / TY, tx = (Xo + TXT - 1) / TXT;
    k_conv32m<<<nI * tz * ty * tx, 128, 0, stream>>>(
        in, tbl, bias, mo, o, Zi, Yi, Xi, Zo, Yo, Xo, tz, ty, tx);
  };

  for (int g0 = 0; g0 < 8; g0 += G) {
    const float* x0g  = x0  + (size_t)g0 * 195000;
    const float* m1g  = m1  + (size_t)g0 * 166098;
    const float* m2g  = m2  + (size_t)g0 * 140184;
    const float* mp1g = mp1 + (size_t)g0 * 110000;
    const float* m3g  = m3  + (size_t)g0 * 90428;
    const float* m4g  = m4  + (size_t)g0 * 73304;
    const float* mp2g = mp2 + (size_t)g0 * 54000;
    const float* m5g  = m5  + (size_t)g0 * 41958;
    const float* m6g  = m6  + (size_t)g0 * 31824;
    const float* m7g  = m7  + (size_t)g0 * 23436;
    const float* mp3g = mp3 + (size_t)g0 * 14688;

    // c1: 50,60,65 -> 47,57,62
    {
      int tz = (47 + TZ - 1) / TZ, ty = (57 + TY - 1) / TY, tx = (62 + TXT - 1) / TXT;
      k_conv1t<<<G * tz * ty * tx, 256, 0, stream>>>(
          x0g, wr1, b1, m1g, A, 50,60,65, 47,57,62, tz, ty, tx);
    }
    // c2 -> 44,54,59
    conv32(A, tb2, b2, m2g, Bb, 47,57,62, 44,54,59, G);
    // p1 -> 40,50,55
    k_pool_z<<<G256((long long)G*127440*8), 256, 0, stream>>>(Bb, m2g,  A,  44,54,59, 40, G);
    k_pool_y<<<G256((long long)G*118000*8), 256, 0, stream>>>(A,  Bb, 40,54,59, 50, G);
    k_pool_x<<<G256((long long)G*110000*8), 256, 0, stream>>>(Bb, mp1g, A,  40,50,59, 55, G);
    // c3 -> 37,47,52
    conv32(A, tb3, b3, m3g, Bb, 40,50,55, 37,47,52, G);
    // c4 -> 34,44,49
    conv32(Bb, tb4, b4, m4g, A, 37,47,52, 34,44,49, G);
    // p2 -> 30,40,45
    k_pool_z<<<G256((long long)G*64680*8), 256, 0, stream>>>(A,  m4g,  Bb, 34,44,49, 30, G);
    k_pool_y<<<G256((long long)G*58800*8), 256, 0, stream>>>(Bb, A,  30,44,49, 40, G);
    k_pool_x<<<G256((long long)G*54000*8), 256, 0, stream>>>(A,  mp2g, Bb, 30,40,49, 45, G);
    // c5 -> 27,37,42
    conv32(Bb, tb5, b5, m5g, A, 30,40,45, 27,37,42, G);
    // c6 -> 24,34,39
    conv32(A, tb6, b6, m6g, Bb, 27,37,42, 24,34,39, G);
    // c7 (32->1) -> 21,31,36
    {
      int tz = (21 + TZ - 1) / TZ, ty = (31 + TY - 1) / TY, tx = (36 + TXT - 1) / TXT;
      k_conv7t<<<G * tz * ty * tx, 256, 0, stream>>>(
          Bb, wr7, b7, m7g, x7, 24,34,39, 21,31,36, tz, ty, tx);
    }
    // p3 -> 17,27,32
    k_pool3<<<G256((long long)G*14688), 256, 0, stream>>>(
        x7, m7g, mp3g, p3 + (size_t)g0 * 14688, G);
  }

  // ---- FC head ----
  k_fc_part<<<dim3(63, 8), 256, 0, stream>>>(p3, W8, part, 14688, 1000, 1836);
  k_fc_fin <<<G256(8000), 256, 0, stream>>>(part, 8, b8, h8, 1000);
  k_fc_part<<<dim3(63, 4), 256, 0, stream>>>(h8, W9, part, 1000, 1000, 250);
  k_fc_fin <<<G256(8000), 256, 0, stream>>>(part, 4, b9, h9, 1000);
  k_fc<<<1, 256, 0, stream>>>(h9, W10, b10, out, 1000, 1);
}